// Round 1
// baseline (9361.372 us; speedup 1.0000x reference)
//
#include <hip/hip_runtime.h>
#include <stdint.h>

// LSTM forward, T=512, B=64, H=800. bf16x3 split-precision MFMA.
//
// ws layout (bytes):
//   [0,           204800)   c state   (64*800 f32)
//   [204800,      307200)   h_hi      (64*800 bf16)
//   [307200,      409600)   h_lo      (64*800 bf16)
//   [409600,      422400)   biasbuf   (100*32 f32)  = b_ih+b_hh in block order
//   [422400,    20902400)   Wbuf      100 u * 50 kt * {hi,lo} * 32x32 bf16 tiles
// total ~20.9 MB

#define T_STEPS 512
#define B_SZ    64
#define H_SZ    800
#define KT_X    25      // k-tiles (of 32) coming from x
#define KT_TOT  50      // + 25 k-tiles from h
#define NU      100     // unit-blocks: 800 / 8

#define OFF_C    0
#define OFF_HHI  204800
#define OFF_HLO  307200
#define OFF_BIAS 409600
#define OFF_WBUF 422400

typedef short bf16x8 __attribute__((ext_vector_type(8)));
typedef float f32x4  __attribute__((ext_vector_type(4)));

__device__ __forceinline__ unsigned short f2bf_rne(float f) {
    unsigned int u = __float_as_uint(f);
    unsigned int r = u + 0x7FFFu + ((u >> 16) & 1u);
    return (unsigned short)(r >> 16);
}
__device__ __forceinline__ float bf2f(unsigned short h) {
    return __uint_as_float(((unsigned int)h) << 16);
}

// ---------------------------------------------------------------------------
// One-time prep: re-order W_ih/W_hh into per-(u,kt) 32x32 bf16 hi/lo tiles in
// exact MFMA fragment order; also fold b_ih+b_hh into biasbuf.
// grid = NU*50 blocks, 256 threads. Virtual row v = gate*8 + unit_within_u.
// ---------------------------------------------------------------------------
__global__ __launch_bounds__(256) void lstm_prep(
        const float* __restrict__ Wih, const float* __restrict__ Whh,
        const float* __restrict__ bih, const float* __restrict__ bhh,
        unsigned short* __restrict__ wbuf, float* __restrict__ biasbuf) {
    int bid = blockIdx.x;
    int u = bid / KT_TOT, kt = bid % KT_TOT;
    int tid = threadIdx.x;
    int vrow = tid >> 3;            // 0..31
    int kk0  = (tid & 7) * 4;       // 0..28
    int g = vrow >> 3, jj = vrow & 7;
    size_t srow = (size_t)g * H_SZ + u * 8 + jj;
    const float* src = (kt < KT_X)
        ? (Wih + srow * H_SZ + kt * 32 + kk0)
        : (Whh + srow * H_SZ + (kt - KT_X) * 32 + kk0);
    float4 v = *(const float4*)src;
    float f[4] = {v.x, v.y, v.z, v.w};
    unsigned short hi[4], lo[4];
#pragma unroll
    for (int i = 0; i < 4; ++i) {
        hi[i] = f2bf_rne(f[i]);
        lo[i] = f2bf_rne(f[i] - bf2f(hi[i]));
    }
    size_t tbase = ((size_t)u * KT_TOT + kt) * 2048;  // elements
    unsigned short* dhi = wbuf + tbase + vrow * 32 + kk0;
    unsigned short* dlo = dhi + 1024;
    *(ushort4*)dhi = make_ushort4(hi[0], hi[1], hi[2], hi[3]);
    *(ushort4*)dlo = make_ushort4(lo[0], lo[1], lo[2], lo[3]);

    if (kt == 0 && tid < 32) {
        int vv = tid;
        size_t r = (size_t)(vv >> 3) * H_SZ + u * 8 + (vv & 7);
        biasbuf[u * 32 + vv] = bih[r] + bhh[r];
    }
}

// ---------------------------------------------------------------------------
// One timestep. grid = 208 blocks (u>=100 exit), 256 threads = 4 waves.
// Block (u, mhalf): gates tile M=32 (batch half) x N=32 (4 gates x 8 units).
// Wave w: (mt,nt) quadrant -> one 16x16 MFMA accumulator, K=1600 in 50 tiles.
// blockIdx mapping pairs (u,mhalf=0/1) onto the same XCD (round-robin assum.)
// so each XCD's L2 holds ~13 W slices (~2.6 MB).
// ---------------------------------------------------------------------------
__global__ __launch_bounds__(256) void lstm_step(
        const float* __restrict__ x, const unsigned short* __restrict__ wbuf,
        const float* __restrict__ biasbuf, unsigned short* __restrict__ hhi,
        unsigned short* __restrict__ hlo, float* __restrict__ cbuf,
        float* __restrict__ out, int t) {
    int bid = blockIdx.x;
    int u = ((bid >> 4) << 3) | (bid & 7);
    int mhalf = (bid >> 3) & 1;
    if (u >= NU) return;

    int tid = threadIdx.x;
    int lane = tid & 63;
    int w = tid >> 6;
    int mt = (w >> 1) & 1, nt = w & 1;
    int rlane = lane & 15;
    int kgrp = (lane >> 4) * 8;
    int brow = mhalf * 32 + mt * 16 + rlane;   // batch row for A fragments

    const float* xrow = x + ((size_t)t * B_SZ + brow) * H_SZ;
    const unsigned short* hhirow = hhi + (size_t)brow * H_SZ;
    const unsigned short* hlorow = hlo + (size_t)brow * H_SZ;
    const unsigned short* wtile =
        wbuf + (size_t)u * KT_TOT * 2048 + (nt * 16 + rlane) * 32 + kgrp;

    f32x4 acc = {0.f, 0.f, 0.f, 0.f};

    // ---- x phase: k-tiles 0..24, split x fp32 -> bf16 hi/lo in-register ----
#pragma unroll 2
    for (int kt = 0; kt < KT_X; ++kt) {
        int k = kt * 32 + kgrp;
        float4 v0 = *(const float4*)(xrow + k);
        float4 v1 = *(const float4*)(xrow + k + 4);
        float f[8] = {v0.x, v0.y, v0.z, v0.w, v1.x, v1.y, v1.z, v1.w};
        bf16x8 ahi, alo;
#pragma unroll
        for (int j = 0; j < 8; ++j) {
            unsigned short h = f2bf_rne(f[j]);
            ahi[j] = (short)h;
            alo[j] = (short)f2bf_rne(f[j] - bf2f(h));
        }
        bf16x8 bhi = *(const bf16x8*)(wtile + (size_t)kt * 2048);
        bf16x8 blo = *(const bf16x8*)(wtile + (size_t)kt * 2048 + 1024);
        acc = __builtin_amdgcn_mfma_f32_16x16x32_bf16(ahi, bhi, acc, 0, 0, 0);
        acc = __builtin_amdgcn_mfma_f32_16x16x32_bf16(ahi, blo, acc, 0, 0, 0);
        acc = __builtin_amdgcn_mfma_f32_16x16x32_bf16(alo, bhi, acc, 0, 0, 0);
    }
    // ---- h phase: k-tiles 25..49, h already split in state buffers ----
#pragma unroll 2
    for (int kt = KT_X; kt < KT_TOT; ++kt) {
        int k = (kt - KT_X) * 32 + kgrp;
        bf16x8 ahi = *(const bf16x8*)(hhirow + k);
        bf16x8 alo = *(const bf16x8*)(hlorow + k);
        bf16x8 bhi = *(const bf16x8*)(wtile + (size_t)kt * 2048);
        bf16x8 blo = *(const bf16x8*)(wtile + (size_t)kt * 2048 + 1024);
        acc = __builtin_amdgcn_mfma_f32_16x16x32_bf16(ahi, bhi, acc, 0, 0, 0);
        acc = __builtin_amdgcn_mfma_f32_16x16x32_bf16(ahi, blo, acc, 0, 0, 0);
        acc = __builtin_amdgcn_mfma_f32_16x16x32_bf16(alo, bhi, acc, 0, 0, 0);
    }

    // ---- epilogue: exchange gates across waves, activations, c/h update ----
    __shared__ float gl[32][33];
    float bv = biasbuf[u * 32 + nt * 16 + rlane];
    int baserow = mt * 16 + (lane >> 4) * 4;    // C/D: row=(lane>>4)*4+j, col=lane&15
#pragma unroll
    for (int j = 0; j < 4; ++j)
        gl[baserow + j][nt * 16 + rlane] = acc[j] + bv;
    __syncthreads();

    int bl = tid >> 3, jl = tid & 7;            // 32 batch-rows x 8 units
    float gi = gl[bl][jl];
    float gf = gl[bl][8 + jl];
    float gg = gl[bl][16 + jl];
    float go = gl[bl][24 + jl];
    int b  = mhalf * 32 + bl;
    int ju = u * 8 + jl;
    size_t sidx = (size_t)b * H_SZ + ju;
    float cold = cbuf[sidx];
    float ig = 1.f / (1.f + __expf(-gi));
    float fg = 1.f / (1.f + __expf(-gf));
    float gt = tanhf(gg);
    float og = 1.f / (1.f + __expf(-go));
    float cn = fg * cold + ig * gt;
    float hn = og * tanhf(cn);
    cbuf[sidx] = cn;
    out[((size_t)t * B_SZ + b) * H_SZ + ju] = hn;
    unsigned short hh = f2bf_rne(hn);
    hhi[sidx] = hh;
    hlo[sidx] = f2bf_rne(hn - bf2f(hh));
}

// ---------------------------------------------------------------------------
extern "C" void kernel_launch(void* const* d_in, const int* in_sizes, int n_in,
                              void* d_out, int out_size, void* d_ws, size_t ws_size,
                              hipStream_t stream) {
    const float* x   = (const float*)d_in[0];
    const float* Wih = (const float*)d_in[1];
    const float* Whh = (const float*)d_in[2];
    const float* bih = (const float*)d_in[3];
    const float* bhh = (const float*)d_in[4];
    float* out = (float*)d_out;

    char* ws = (char*)d_ws;
    float* cbuf            = (float*)(ws + OFF_C);
    unsigned short* hhi    = (unsigned short*)(ws + OFF_HHI);
    unsigned short* hlo    = (unsigned short*)(ws + OFF_HLO);
    float* biasbuf         = (float*)(ws + OFF_BIAS);
    unsigned short* wbuf   = (unsigned short*)(ws + OFF_WBUF);

    // zero c, h_hi, h_lo (ws is poisoned 0xAA before every timed call)
    hipMemsetAsync(ws, 0, OFF_BIAS, stream);

    lstm_prep<<<NU * KT_TOT, 256, 0, stream>>>(Wih, Whh, bih, bhh, wbuf, biasbuf);

    for (int t = 0; t < T_STEPS; ++t)
        lstm_step<<<208, 256, 0, stream>>>(x, wbuf, biasbuf, hhi, hlo, cbuf, out, t);
}